// Round 1
// baseline (4633.824 us; speedup 1.0000x reference)
//
#include <hip/hip_runtime.h>
#include <cmath>

#define N_GRAPHS 64

// ---------------------------------------------------------------------------
// Per-node split of EdgeConv layer 1:
//   h1(edge) = relu( x[dst] @ (W1_top - W1_bot) + b1  +  x[src] @ W1_bot )
//            = relu( P[dst] + Q[src] )
// ---------------------------------------------------------------------------
template<int F, int H>
__global__ __launch_bounds__(256) void node_pq(
    const float* __restrict__ x, const float* __restrict__ w1,
    const float* __restrict__ b1, float* __restrict__ P,
    float* __restrict__ Q, int nNodes)
{
    int idx = blockIdx.x * 256 + threadIdx.x;
    if (idx >= nNodes * H) return;
    int n = idx / H, h = idx - n * H;
    float p = b1[h], q = 0.f;
#pragma unroll 8
    for (int k = 0; k < F; ++k) {
        float xv = x[n * F + k];          // broadcast across the H lanes of a row
        float wt = w1[k * H + h];         // coalesced
        float wb = w1[(F + k) * H + h];   // coalesced
        p += xv * (wt - wb);
        q += xv * wb;
    }
    P[idx] = p;
    Q[idx] = q;
}

// ---------------------------------------------------------------------------
// Per-edge MLP (layers 2 and 3) + scatter-add.
//   T edges per block, h1/h2 staged in LDS row-major [T][H].
//   Thread micro-tile: 4 edges x TJ output features.
// ---------------------------------------------------------------------------
template<int H, int T, int TJ>
__global__ __launch_bounds__(256) void edge_mlp(
    const float* __restrict__ P, const float* __restrict__ Q,
    const int* __restrict__ esrc, const int* __restrict__ edst,
    const float* __restrict__ W2, const float* __restrict__ b2,
    const float* __restrict__ W3, const float* __restrict__ b3,
    float* __restrict__ outx, int nE)
{
    constexpr int NJ = H / TJ;       // j-tiles
    constexpr int NT = 256 / NJ;     // t-tiles
    constexpr int TT = T / NT;       // edges per thread (== 4 for our configs)
    static_assert(TT == 4, "tiling assumes 4 edges per thread");
    static_assert(NJ * NT == 256, "block size");

    __shared__ float A[T][H];
    __shared__ float B[T][H];
    __shared__ int sdst[T];
    __shared__ int ssrc[T];

    const int tid = threadIdx.x;
    const int e0  = blockIdx.x * T;
    int nvalid = nE - e0; if (nvalid > T) nvalid = T;

    if (tid < T)            sdst[tid]     = (e0 + tid     < nE) ? edst[e0 + tid]     : 0;
    else if (tid < 2 * T)   ssrc[tid - T] = (e0 + tid - T < nE) ? esrc[e0 + tid - T] : 0;
    __syncthreads();

    // phase 1: h1 = relu(P[dst] + Q[src])   (coalesced row gathers)
    for (int idx = tid; idx < T * H; idx += 256) {
        int t = idx / H, k = idx - t * H;
        float v = P[(size_t)sdst[t] * H + k] + Q[(size_t)ssrc[t] * H + k];
        A[t][k] = fmaxf(v, 0.f);
    }
    __syncthreads();

    const int jt = tid % NJ, tt = tid / NJ;
    const int j0 = jt * TJ, t0 = tt * TT;

    // phase 2: h2 = relu(h1 @ W2 + b2)
    {
        float acc[TT][TJ];
#pragma unroll
        for (int a = 0; a < TT; ++a)
#pragma unroll
            for (int b = 0; b < TJ; ++b) acc[a][b] = b2[j0 + b];

#pragma unroll 2
        for (int k = 0; k < H; ++k) {
            float hv[TT];
#pragma unroll
            for (int a = 0; a < TT; ++a) hv[a] = A[t0 + a][k];   // LDS broadcast
            float w[TJ];
#pragma unroll
            for (int b4 = 0; b4 < TJ; b4 += 4)
                *(float4*)&w[b4] = *(const float4*)&W2[(size_t)k * H + j0 + b4];
#pragma unroll
            for (int a = 0; a < TT; ++a)
#pragma unroll
                for (int b = 0; b < TJ; ++b) acc[a][b] += hv[a] * w[b];
        }
#pragma unroll
        for (int a = 0; a < TT; ++a)
#pragma unroll
            for (int b = 0; b < TJ; ++b) B[t0 + a][j0 + b] = fmaxf(acc[a][b], 0.f);
    }
    __syncthreads();

    // phase 3: m = h2 @ W3 + b3 ; scatter-add into node accumulator
    {
        float acc[TT][TJ];
#pragma unroll
        for (int a = 0; a < TT; ++a)
#pragma unroll
            for (int b = 0; b < TJ; ++b) acc[a][b] = b3[j0 + b];

#pragma unroll 2
        for (int k = 0; k < H; ++k) {
            float hv[TT];
#pragma unroll
            for (int a = 0; a < TT; ++a) hv[a] = B[t0 + a][k];
            float w[TJ];
#pragma unroll
            for (int b4 = 0; b4 < TJ; b4 += 4)
                *(float4*)&w[b4] = *(const float4*)&W3[(size_t)k * H + j0 + b4];
#pragma unroll
            for (int a = 0; a < TT; ++a)
#pragma unroll
                for (int b = 0; b < TJ; ++b) acc[a][b] += hv[a] * w[b];
        }
#pragma unroll
        for (int a = 0; a < TT; ++a) {
            if (t0 + a < nvalid) {
                int d = sdst[t0 + a];
#pragma unroll
                for (int b = 0; b < TJ; ++b)
                    atomicAdd(&outx[(size_t)d * H + j0 + b], acc[a][b]);
            }
        }
    }
}

// ---------------------------------------------------------------------------
// Global mean pool: per-node block adds its row into its graph's sum.
// ---------------------------------------------------------------------------
__global__ __launch_bounds__(256) void pool_sum(
    const float* __restrict__ x3, const int* __restrict__ batch,
    float* __restrict__ gsum, float* __restrict__ gcnt, int nNodes)
{
    int n = blockIdx.x;
    if (n >= nNodes) return;
    int g = batch[n];
    atomicAdd(&gsum[g * 256 + threadIdx.x], x3[(size_t)n * 256 + threadIdx.x]);
    if (threadIdx.x == 0) atomicAdd(&gcnt[g], 1.0f);
}

// ---------------------------------------------------------------------------
// Head: g = sum/cnt ; h = g@l2+b ; out = sigmoid(h@l3+b). One block.
// ---------------------------------------------------------------------------
__global__ __launch_bounds__(256) void head(
    const float* __restrict__ gsum, const float* __restrict__ gcnt,
    const float* __restrict__ l2w, const float* __restrict__ l2b,
    const float* __restrict__ l3w, const float* __restrict__ l3b,
    float* __restrict__ out)
{
    __shared__ float g[N_GRAPHS * 256];
    __shared__ float h[N_GRAPHS * 64];
    int tid = threadIdx.x;
    for (int i = tid; i < N_GRAPHS * 256; i += 256) {
        int gi = i / 256;
        float c = gcnt[gi];
        g[i] = gsum[i] / fmaxf(c, 1.f);
    }
    __syncthreads();
    for (int i = tid; i < N_GRAPHS * 64; i += 256) {
        int r = i / 64, c = i - r * 64;
        float acc = l2b[c];
#pragma unroll 4
        for (int k = 0; k < 256; ++k) acc += g[r * 256 + k] * l2w[k * 64 + c];
        h[i] = acc;
    }
    __syncthreads();
    for (int i = tid; i < N_GRAPHS * 2; i += 256) {
        int r = i / 2, c = i - r * 2;
        float acc = l3b[c];
#pragma unroll 4
        for (int k = 0; k < 64; ++k) acc += h[r * 64 + k] * l3w[k * 2 + c];
        out[i] = 1.f / (1.f + expf(-acc));
    }
}

// ---------------------------------------------------------------------------
extern "C" void kernel_launch(void* const* d_in, const int* in_sizes, int n_in,
                              void* d_out, int out_size, void* d_ws, size_t ws_size,
                              hipStream_t stream)
{
    const float* x     = (const float*)d_in[0];
    const int*   ei    = (const int*)d_in[1];
    const int*   batch = (const int*)d_in[2];
    const float* c1_w1 = (const float*)d_in[3];
    const float* c1_b1 = (const float*)d_in[4];
    const float* c1_w2 = (const float*)d_in[5];
    const float* c1_b2 = (const float*)d_in[6];
    const float* c1_w3 = (const float*)d_in[7];
    const float* c1_b3 = (const float*)d_in[8];
    const float* c2_w1 = (const float*)d_in[9];
    const float* c2_b1 = (const float*)d_in[10];
    const float* c2_w2 = (const float*)d_in[11];
    const float* c2_b2 = (const float*)d_in[12];
    const float* c2_w3 = (const float*)d_in[13];
    const float* c2_b3 = (const float*)d_in[14];
    const float* c3_w1 = (const float*)d_in[15];
    const float* c3_b1 = (const float*)d_in[16];
    const float* c3_w2 = (const float*)d_in[17];
    const float* c3_b2 = (const float*)d_in[18];
    const float* c3_w3 = (const float*)d_in[19];
    const float* c3_b3 = (const float*)d_in[20];
    const float* l2w   = (const float*)d_in[21];
    const float* l2b   = (const float*)d_in[22];
    const float* l3w   = (const float*)d_in[23];
    const float* l3b   = (const float*)d_in[24];
    float* out = (float*)d_out;

    const int N = in_sizes[0] / 3;
    const int E = in_sizes[1] / 2;
    const int* src = ei;        // edge_index[0] = source j
    const int* dst = ei + E;    // edge_index[1] = target i

    // workspace layout (floats):
    // [ x1 (N*64) | x2 (N*128) | x3 (N*256) | gsum (64*256) | gcnt (64) | P (N*256) | Q (N*256) ]
    float* ws   = (float*)d_ws;
    float* x1   = ws;
    float* x2   = x1 + (size_t)N * 64;
    float* x3   = x2 + (size_t)N * 128;
    float* gsum = x3 + (size_t)N * 256;
    float* gcnt = gsum + (size_t)N_GRAPHS * 256;
    float* Pb   = gcnt + N_GRAPHS;
    float* Qb   = Pb + (size_t)N * 256;

    // zero the accumulation buffers (x1,x2,x3,gsum,gcnt are contiguous)
    size_t zero_bytes = ((size_t)N * (64 + 128 + 256) + (size_t)N_GRAPHS * 256 + N_GRAPHS) * sizeof(float);
    hipMemsetAsync(d_ws, 0, zero_bytes, stream);

    // conv1: 3 -> 64
    node_pq<3, 64><<<(N * 64 + 255) / 256, 256, 0, stream>>>(x, c1_w1, c1_b1, Pb, Qb, N);
    edge_mlp<64, 64, 4><<<(E + 63) / 64, 256, 0, stream>>>(Pb, Qb, src, dst, c1_w2, c1_b2, c1_w3, c1_b3, x1, E);

    // conv2: 64 -> 128
    node_pq<64, 128><<<(N * 128 + 255) / 256, 256, 0, stream>>>(x1, c2_w1, c2_b1, Pb, Qb, N);
    edge_mlp<128, 64, 8><<<(E + 63) / 64, 256, 0, stream>>>(Pb, Qb, src, dst, c2_w2, c2_b2, c2_w3, c2_b3, x2, E);

    // conv3: 128 -> 256
    node_pq<128, 256><<<(N * 256 + 255) / 256, 256, 0, stream>>>(x2, c3_w1, c3_b1, Pb, Qb, N);
    edge_mlp<256, 32, 8><<<(E + 31) / 32, 256, 0, stream>>>(Pb, Qb, src, dst, c3_w2, c3_b2, c3_w3, c3_b3, x3, E);

    // pool + head
    pool_sum<<<N, 256, 0, stream>>>(x3, batch, gsum, gcnt, N);
    head<<<1, 256, 0, stream>>>(gsum, gcnt, l2w, l2b, l3w, l3b, out);
}

// Round 2
// 748.048 us; speedup vs baseline: 6.1946x; 6.1946x over previous
//
#include <hip/hip_runtime.h>
#include <cmath>

#define N_GRAPHS 64

typedef _Float16 f16x8 __attribute__((ext_vector_type(8)));
typedef float f32x4 __attribute__((ext_vector_type(4)));

// ---------------------------------------------------------------------------
// Counting sort of edges by dst: histogram -> single-block scan -> scatter.
// ---------------------------------------------------------------------------
__global__ __launch_bounds__(256) void build_hist(
    const int* __restrict__ dst, int* __restrict__ hist, int E)
{
    int i = blockIdx.x * 256 + threadIdx.x;
    if (i < E) atomicAdd(&hist[dst[i]], 1);
}

__global__ __launch_bounds__(1024) void scan_deg(
    const int* __restrict__ hist, int* __restrict__ cursor, int N)
{
    __shared__ int part[1024];
    int tid = threadIdx.x;
    int per = (N + 1023) / 1024;
    int base = tid * per;
    int s = 0;
    for (int i = 0; i < per; ++i) { int idx = base + i; if (idx < N) s += hist[idx]; }
    part[tid] = s;
    __syncthreads();
    for (int off = 1; off < 1024; off <<= 1) {
        int v = (tid >= off) ? part[tid - off] : 0;
        __syncthreads();
        part[tid] += v;
        __syncthreads();
    }
    int run = part[tid] - s;   // exclusive prefix for this thread's chunk
    for (int i = 0; i < per; ++i) {
        int idx = base + i;
        if (idx < N) { cursor[idx] = run; run += hist[idx]; }
    }
}

__global__ __launch_bounds__(256) void scatter_edges(
    const int* __restrict__ src, const int* __restrict__ dst,
    int* __restrict__ cursor, int* __restrict__ ssrc, int* __restrict__ sdst, int E)
{
    int i = blockIdx.x * 256 + threadIdx.x;
    if (i >= E) return;
    int d = dst[i];
    int pos = atomicAdd(&cursor[d], 1);
    ssrc[pos] = src[i];
    sdst[pos] = d;
}

// ---------------------------------------------------------------------------
// W2 [K][N] fp32 -> W2T [N][K] f16  (B^T layout for contiguous-K B-fragments)
// ---------------------------------------------------------------------------
template<int H>
__global__ __launch_bounds__(256) void w2_to_t(
    const float* __restrict__ w2, _Float16* __restrict__ wt)
{
    int idx = blockIdx.x * 256 + threadIdx.x;
    if (idx >= H * H) return;
    int n = idx / H, k = idx % H;
    wt[idx] = (_Float16)w2[k * H + n];
}

// ---------------------------------------------------------------------------
// node_pq: P = x@(W1_top - W1_bot) + b1 ; Q = x@W1_bot   (fp32, 4-wide)
// ---------------------------------------------------------------------------
template<int F, int H>
__global__ __launch_bounds__(256) void node_pq4(
    const float* __restrict__ x, const float* __restrict__ w1,
    const float* __restrict__ b1, float* __restrict__ P,
    float* __restrict__ Q, int nNodes)
{
    int idx = blockIdx.x * 256 + threadIdx.x;
    int total = nNodes * (H / 4);
    if (idx >= total) return;
    int n = idx / (H / 4), j4 = (idx % (H / 4)) * 4;
    float4 p = *(const float4*)&b1[j4];
    float4 q = make_float4(0.f, 0.f, 0.f, 0.f);
    for (int k = 0; k < F; ++k) {
        float xv = x[(size_t)n * F + k];
        float4 wt = *(const float4*)&w1[(size_t)k * H + j4];
        float4 wb = *(const float4*)&w1[(size_t)(F + k) * H + j4];
        p.x += xv * (wt.x - wb.x); q.x += xv * wb.x;
        p.y += xv * (wt.y - wb.y); q.y += xv * wb.y;
        p.z += xv * (wt.z - wb.z); q.z += xv * wb.z;
        p.w += xv * (wt.w - wb.w); q.w += xv * wb.w;
    }
    *(float4*)&P[(size_t)n * H + j4] = p;
    *(float4*)&Q[(size_t)n * H + j4] = q;
}

// ---------------------------------------------------------------------------
// Per-edge layer-2 via MFMA + in-tile segmented reduction of h2 by dst.
//   64 sorted edges per block, 4 waves; wave w owns cols [w*H/4, (w+1)*H/4).
//   A (h1, f16, XOR-swizzled) lives in the low half of the f32 dump buffer S.
// ---------------------------------------------------------------------------
template<int H>
__global__ __launch_bounds__(256) void edge_mfma(
    const float* __restrict__ P, const float* __restrict__ Q,
    const int* __restrict__ ssrc, const int* __restrict__ sdst,
    const _Float16* __restrict__ W2T, const float* __restrict__ b2,
    float* __restrict__ h2sum, int nE)
{
    constexpr int T = 64;
    constexpr int KCH = H / 8;        // 16B chunks per A row
    constexpr int NFRAG = H / 64;     // 16-col fragments per wave
    constexpr int KSTEPS = H / 32;
    constexpr int NCH = 256 / H;      // column-chunks in reduce phase
    constexpr int RPC = T / NCH;      // rows per chunk
    static_assert(H % 64 == 0, "H multiple of 64");

    __shared__ float S[T * H];                 // f32 h2 dump; low half doubles as A
    _Float16* A = (_Float16*)S;                // A[64][H] f16, byte ^= ((row&7)<<4)
    __shared__ int s_dst[T];
    __shared__ int s_src[T];

    const int tid = threadIdx.x;
    const int e0 = blockIdx.x * T;
    int nvalid = nE - e0; if (nvalid > T) nvalid = T;

    if (tid < T) { int e = e0 + tid; s_dst[tid] = (e < nE) ? sdst[e] : sdst[nE - 1]; }
    else if (tid < 2 * T) { int e = e0 + tid - T; s_src[tid - T] = (e < nE) ? ssrc[e] : 0; }
    __syncthreads();

    // gather + h1 = relu(P[dst] + Q[src]) -> f16 -> swizzled LDS
    for (int q = tid; q < T * KCH; q += 256) {
        int row = q / KCH, kc = q % KCH;
        const float* pr = P + (size_t)s_dst[row] * H + kc * 8;
        const float* qr = Q + (size_t)s_src[row] * H + kc * 8;
        float4 p0 = *(const float4*)pr, p1 = *(const float4*)(pr + 4);
        float4 q0 = *(const float4*)qr, q1 = *(const float4*)(qr + 4);
        f16x8 h;
        h[0] = (_Float16)fmaxf(p0.x + q0.x, 0.f);
        h[1] = (_Float16)fmaxf(p0.y + q0.y, 0.f);
        h[2] = (_Float16)fmaxf(p0.z + q0.z, 0.f);
        h[3] = (_Float16)fmaxf(p0.w + q0.w, 0.f);
        h[4] = (_Float16)fmaxf(p1.x + q1.x, 0.f);
        h[5] = (_Float16)fmaxf(p1.y + q1.y, 0.f);
        h[6] = (_Float16)fmaxf(p1.z + q1.z, 0.f);
        h[7] = (_Float16)fmaxf(p1.w + q1.w, 0.f);
        int byte = row * (2 * H) + kc * 16;
        byte ^= ((row & 7) << 4);
        *(f16x8*)((char*)A + byte) = h;
    }
    __syncthreads();

    // MFMA: h2_pre = h1 @ W2 + b2   (A: M=64 x K=H ; B: K=H x N=H/4 per wave)
    const int wave = tid >> 6, lane = tid & 63;
    const int c0 = wave * (H / 4);
    const int lr = lane & 15;
    const int kg = lane >> 4;

    f32x4 acc[4][NFRAG];
    for (int n = 0; n < NFRAG; ++n) {
        float bv = b2[c0 + n * 16 + lr];
        for (int m = 0; m < 4; ++m) acc[m][n] = (f32x4){bv, bv, bv, bv};
    }

    for (int ks = 0; ks < KSTEPS; ++ks) {
        const int k0 = ks * 32 + kg * 8;
        f16x8 af[4];
#pragma unroll
        for (int m = 0; m < 4; ++m) {
            int row = m * 16 + lr;
            int byte = row * (2 * H) + k0 * 2;
            byte ^= ((row & 7) << 4);
            af[m] = *(const f16x8*)((char*)A + byte);
        }
        f16x8 bf[NFRAG];
#pragma unroll
        for (int n = 0; n < NFRAG; ++n)
            bf[n] = *(const f16x8*)&W2T[(size_t)(c0 + n * 16 + lr) * H + k0];
#pragma unroll
        for (int m = 0; m < 4; ++m)
#pragma unroll
            for (int n = 0; n < NFRAG; ++n)
                acc[m][n] = __builtin_amdgcn_mfma_f32_16x16x32_f16(af[m], bf[n], acc[m][n], 0, 0, 0);
    }
    __syncthreads();   // all waves done reading A before S overwrite

    // dump h2 = relu(acc) to S.  C/D layout: col = lane&15, row = (lane>>4)*4 + j
#pragma unroll
    for (int m = 0; m < 4; ++m)
#pragma unroll
        for (int n = 0; n < NFRAG; ++n) {
            int col = c0 + n * 16 + lr;
#pragma unroll
            for (int j = 0; j < 4; ++j) {
                int row = m * 16 + kg * 4 + j;
                S[row * H + col] = fmaxf(acc[m][n][j], 0.f);
            }
        }
    __syncthreads();

    // segmented (sorted-dst) column reduction; one atomic per segment per col
    {
        int c = tid % H;
        int ch = tid / H;
        int r0 = ch * RPC;
        int rend = r0 + RPC; if (rend > nvalid) rend = nvalid;
        if (r0 < nvalid) {
            int cur = s_dst[r0];
            float a = 0.f;
            for (int r = r0; r < rend; ++r) {
                int d = s_dst[r];
                if (d != cur) {
                    atomicAdd(&h2sum[(size_t)cur * H + c], a);
                    a = 0.f; cur = d;
                }
                a += S[r * H + c];
            }
            atomicAdd(&h2sum[(size_t)cur * H + c], a);
        }
    }
}

// ---------------------------------------------------------------------------
// x_out = h2sum @ W3 + deg * b3   (fp32, 4-wide)
// ---------------------------------------------------------------------------
template<int H>
__global__ __launch_bounds__(256) void w3_apply4(
    const float* __restrict__ h2sum, const float* __restrict__ w3,
    const float* __restrict__ b3, const int* __restrict__ deg,
    float* __restrict__ xout, int nNodes)
{
    int idx = blockIdx.x * 256 + threadIdx.x;
    int total = nNodes * (H / 4);
    if (idx >= total) return;
    int n = idx / (H / 4), j4 = (idx % (H / 4)) * 4;
    float dg = (float)deg[n];
    float4 b = *(const float4*)&b3[j4];
    float4 a = make_float4(b.x * dg, b.y * dg, b.z * dg, b.w * dg);
    const float* hr = h2sum + (size_t)n * H;
    for (int k = 0; k < H; ++k) {
        float s = hr[k];
        float4 w = *(const float4*)&w3[(size_t)k * H + j4];
        a.x += s * w.x; a.y += s * w.y; a.z += s * w.z; a.w += s * w.w;
    }
    *(float4*)&xout[(size_t)n * H + j4] = a;
}

// ---------------------------------------------------------------------------
// Global mean pool + head (unchanged from round 1)
// ---------------------------------------------------------------------------
__global__ __launch_bounds__(256) void pool_sum(
    const float* __restrict__ x3, const int* __restrict__ batch,
    float* __restrict__ gsum, float* __restrict__ gcnt, int nNodes)
{
    int n = blockIdx.x;
    if (n >= nNodes) return;
    int g = batch[n];
    atomicAdd(&gsum[g * 256 + threadIdx.x], x3[(size_t)n * 256 + threadIdx.x]);
    if (threadIdx.x == 0) atomicAdd(&gcnt[g], 1.0f);
}

__global__ __launch_bounds__(256) void head(
    const float* __restrict__ gsum, const float* __restrict__ gcnt,
    const float* __restrict__ l2w, const float* __restrict__ l2b,
    const float* __restrict__ l3w, const float* __restrict__ l3b,
    float* __restrict__ out)
{
    __shared__ float g[N_GRAPHS * 256];
    __shared__ float h[N_GRAPHS * 64];
    int tid = threadIdx.x;
    for (int i = tid; i < N_GRAPHS * 256; i += 256) {
        int gi = i / 256;
        float c = gcnt[gi];
        g[i] = gsum[i] / fmaxf(c, 1.f);
    }
    __syncthreads();
    for (int i = tid; i < N_GRAPHS * 64; i += 256) {
        int r = i / 64, c = i - r * 64;
        float acc = l2b[c];
#pragma unroll 4
        for (int k = 0; k < 256; ++k) acc += g[r * 256 + k] * l2w[k * 64 + c];
        h[i] = acc;
    }
    __syncthreads();
    for (int i = tid; i < N_GRAPHS * 2; i += 256) {
        int r = i / 2, c = i - r * 2;
        float acc = l3b[c];
#pragma unroll 4
        for (int k = 0; k < 64; ++k) acc += h[r * 64 + k] * l3w[k * 2 + c];
        out[i] = 1.f / (1.f + expf(-acc));
    }
}

// ---------------------------------------------------------------------------
extern "C" void kernel_launch(void* const* d_in, const int* in_sizes, int n_in,
                              void* d_out, int out_size, void* d_ws, size_t ws_size,
                              hipStream_t stream)
{
    const float* x     = (const float*)d_in[0];
    const int*   ei    = (const int*)d_in[1];
    const int*   batch = (const int*)d_in[2];
    const float* c1_w1 = (const float*)d_in[3];
    const float* c1_b1 = (const float*)d_in[4];
    const float* c1_w2 = (const float*)d_in[5];
    const float* c1_b2 = (const float*)d_in[6];
    const float* c1_w3 = (const float*)d_in[7];
    const float* c1_b3 = (const float*)d_in[8];
    const float* c2_w1 = (const float*)d_in[9];
    const float* c2_b1 = (const float*)d_in[10];
    const float* c2_w2 = (const float*)d_in[11];
    const float* c2_b2 = (const float*)d_in[12];
    const float* c2_w3 = (const float*)d_in[13];
    const float* c2_b3 = (const float*)d_in[14];
    const float* c3_w1 = (const float*)d_in[15];
    const float* c3_b1 = (const float*)d_in[16];
    const float* c3_w2 = (const float*)d_in[17];
    const float* c3_b2 = (const float*)d_in[18];
    const float* c3_w3 = (const float*)d_in[19];
    const float* c3_b3 = (const float*)d_in[20];
    const float* l2w   = (const float*)d_in[21];
    const float* l2b   = (const float*)d_in[22];
    const float* l3w   = (const float*)d_in[23];
    const float* l3b   = (const float*)d_in[24];
    float* out = (float*)d_out;

    const int N = in_sizes[0] / 3;
    const int E = in_sizes[1] / 2;
    const int* src = ei;        // edge_index[0] = source j
    const int* dst = ei + E;    // edge_index[1] = target i

    // workspace layout
    float* ws   = (float*)d_ws;
    float* x1   = ws;                          // N*64
    float* x2   = x1 + (size_t)N * 64;         // N*128
    float* x3   = x2 + (size_t)N * 128;        // N*256
    float* Pb   = x3 + (size_t)N * 256;        // N*256
    float* Qb   = Pb + (size_t)N * 256;        // N*256
    float* h2s1 = Qb + (size_t)N * 256;        // N*64   -- zeroed region starts here
    float* h2s2 = h2s1 + (size_t)N * 64;       // N*128
    float* h2s3 = h2s2 + (size_t)N * 128;      // N*256
    float* gsum = h2s3 + (size_t)N * 256;      // 64*256
    float* gcnt = gsum + (size_t)N_GRAPHS * 256;  // 64
    int*   hist   = (int*)(gcnt + N_GRAPHS);   // N  (also deg)
    int*   cursor = hist + N;                  // N  -- zeroed region ends at hist end
    int*   ssrcb  = cursor + N;                // E
    int*   sdstb  = ssrcb + E;                 // E
    _Float16* wt  = (_Float16*)(sdstb + E);    // 256*256

    // zero h2s1..gcnt (floats) + hist (ints) in one contiguous memset
    size_t zero_bytes = ((size_t)N * (64 + 128 + 256) + (size_t)N_GRAPHS * 256 + N_GRAPHS) * sizeof(float)
                      + (size_t)N * sizeof(int);
    hipMemsetAsync(h2s1, 0, zero_bytes, stream);

    // sort edges by dst
    build_hist<<<(E + 255) / 256, 256, 0, stream>>>(dst, hist, E);
    scan_deg<<<1, 1024, 0, stream>>>(hist, cursor, N);
    scatter_edges<<<(E + 255) / 256, 256, 0, stream>>>(src, dst, cursor, ssrcb, sdstb, E);

    const int EB = (E + 63) / 64;

    // conv1: 3 -> 64
    node_pq4<3, 64><<<(N * 16 + 255) / 256, 256, 0, stream>>>(x, c1_w1, c1_b1, Pb, Qb, N);
    w2_to_t<64><<<(64 * 64 + 255) / 256, 256, 0, stream>>>(c1_w2, wt);
    edge_mfma<64><<<EB, 256, 0, stream>>>(Pb, Qb, ssrcb, sdstb, wt, c1_b2, h2s1, E);
    w3_apply4<64><<<(N * 16 + 255) / 256, 256, 0, stream>>>(h2s1, c1_w3, c1_b3, hist, x1, N);

    // conv2: 64 -> 128
    node_pq4<64, 128><<<(N * 32 + 255) / 256, 256, 0, stream>>>(x1, c2_w1, c2_b1, Pb, Qb, N);
    w2_to_t<128><<<(128 * 128 + 255) / 256, 256, 0, stream>>>(c2_w2, wt);
    edge_mfma<128><<<EB, 256, 0, stream>>>(Pb, Qb, ssrcb, sdstb, wt, c2_b2, h2s2, E);
    w3_apply4<128><<<(N * 32 + 255) / 256, 256, 0, stream>>>(h2s2, c2_w3, c2_b3, hist, x2, N);

    // conv3: 128 -> 256
    node_pq4<128, 256><<<(N * 64 + 255) / 256, 256, 0, stream>>>(x2, c3_w1, c3_b1, Pb, Qb, N);
    w2_to_t<256><<<(256 * 256 + 255) / 256, 256, 0, stream>>>(c3_w2, wt);
    edge_mfma<256><<<EB, 256, 0, stream>>>(Pb, Qb, ssrcb, sdstb, wt, c3_b2, h2s3, E);
    w3_apply4<256><<<(N * 64 + 255) / 256, 256, 0, stream>>>(h2s3, c3_w3, c3_b3, hist, x3, N);

    // pool + head
    pool_sum<<<N, 256, 0, stream>>>(x3, batch, gsum, gcnt, N);
    head<<<1, 256, 0, stream>>>(gsum, gcnt, l2w, l2b, l3w, l3b, out);
}

// Round 3
// 656.592 us; speedup vs baseline: 7.0574x; 1.1393x over previous
//
#include <hip/hip_runtime.h>
#include <cmath>

#define N_GRAPHS 64

typedef _Float16 f16x8 __attribute__((ext_vector_type(8)));
typedef _Float16 f16x4 __attribute__((ext_vector_type(4)));
typedef float f32x4 __attribute__((ext_vector_type(4)));

// ---------------------------------------------------------------------------
// Counting sort of edges by dst: histogram -> single-block scan -> scatter.
// ---------------------------------------------------------------------------
__global__ __launch_bounds__(256) void build_hist(
    const int* __restrict__ dst, int* __restrict__ hist, int E)
{
    int i = blockIdx.x * 256 + threadIdx.x;
    if (i < E) atomicAdd(&hist[dst[i]], 1);
}

__global__ __launch_bounds__(1024) void scan_deg(
    const int* __restrict__ hist, int* __restrict__ cursor, int N)
{
    __shared__ int part[1024];
    int tid = threadIdx.x;
    int per = (N + 1023) / 1024;
    int base = tid * per;
    int s = 0;
    for (int i = 0; i < per; ++i) { int idx = base + i; if (idx < N) s += hist[idx]; }
    part[tid] = s;
    __syncthreads();
    for (int off = 1; off < 1024; off <<= 1) {
        int v = (tid >= off) ? part[tid - off] : 0;
        __syncthreads();
        part[tid] += v;
        __syncthreads();
    }
    int run = part[tid] - s;
    for (int i = 0; i < per; ++i) {
        int idx = base + i;
        if (idx < N) { cursor[idx] = run; run += hist[idx]; }
    }
}

__global__ __launch_bounds__(256) void scatter_edges(
    const int* __restrict__ src, const int* __restrict__ dst,
    int* __restrict__ cursor, int* __restrict__ ssrc, int* __restrict__ sdst, int E)
{
    int i = blockIdx.x * 256 + threadIdx.x;
    if (i >= E) return;
    int d = dst[i];
    int pos = atomicAdd(&cursor[d], 1);
    ssrc[pos] = src[i];
    sdst[pos] = d;
}

// ---------------------------------------------------------------------------
// W2 [K][N] fp32 -> W2T [N][K] f16
// ---------------------------------------------------------------------------
template<int H>
__global__ __launch_bounds__(256) void w2_to_t(
    const float* __restrict__ w2, _Float16* __restrict__ wt)
{
    int idx = blockIdx.x * 256 + threadIdx.x;
    if (idx >= H * H) return;
    int n = idx / H, k = idx % H;
    wt[idx] = (_Float16)w2[k * H + n];
}

// ---------------------------------------------------------------------------
// node_pq: P = x@(W1_top - W1_bot) + b1 ; Q = x@W1_bot   -> f16 outputs
// ---------------------------------------------------------------------------
template<int F, int H>
__global__ __launch_bounds__(256) void node_pqh(
    const float* __restrict__ x, const float* __restrict__ w1,
    const float* __restrict__ b1, _Float16* __restrict__ P,
    _Float16* __restrict__ Q, int nNodes)
{
    int idx = blockIdx.x * 256 + threadIdx.x;
    int total = nNodes * (H / 8);
    if (idx >= total) return;
    int n = idx / (H / 8), j8 = (idx % (H / 8)) * 8;
    float p[8], q[8];
#pragma unroll
    for (int j = 0; j < 8; ++j) { p[j] = b1[j8 + j]; q[j] = 0.f; }
    for (int k = 0; k < F; ++k) {
        float xv = x[(size_t)n * F + k];
        const float* wt = &w1[(size_t)k * H + j8];
        const float* wb = &w1[(size_t)(F + k) * H + j8];
        float4 t0 = *(const float4*)wt, t1 = *(const float4*)(wt + 4);
        float4 b0 = *(const float4*)wb, b1v = *(const float4*)(wb + 4);
        p[0] += xv * (t0.x - b0.x);  q[0] += xv * b0.x;
        p[1] += xv * (t0.y - b0.y);  q[1] += xv * b0.y;
        p[2] += xv * (t0.z - b0.z);  q[2] += xv * b0.z;
        p[3] += xv * (t0.w - b0.w);  q[3] += xv * b0.w;
        p[4] += xv * (t1.x - b1v.x); q[4] += xv * b1v.x;
        p[5] += xv * (t1.y - b1v.y); q[5] += xv * b1v.y;
        p[6] += xv * (t1.z - b1v.z); q[6] += xv * b1v.z;
        p[7] += xv * (t1.w - b1v.w); q[7] += xv * b1v.w;
    }
    f16x8 ph, qh;
#pragma unroll
    for (int j = 0; j < 8; ++j) { ph[j] = (_Float16)p[j]; qh[j] = (_Float16)q[j]; }
    *(f16x8*)&P[(size_t)n * H + j8] = ph;
    *(f16x8*)&Q[(size_t)n * H + j8] = qh;
}

// ---------------------------------------------------------------------------
// Per-edge layer-2 MFMA + in-tile segmented reduction.
//   A: f16 [64][H] row-major, XOR-swizzled (byte ^= (row&7)<<4)
//   S: f16 col-major [H][68] (pitch 68 = 64 rows + 4 pad), overlaps A.
// ---------------------------------------------------------------------------
template<int H>
__global__ __launch_bounds__(256, 4) void edge_mfma(
    const _Float16* __restrict__ P, const _Float16* __restrict__ Q,
    const int* __restrict__ ssrc, const int* __restrict__ sdst,
    const _Float16* __restrict__ W2T, const float* __restrict__ b2,
    float* __restrict__ h2sum, int nE)
{
    constexpr int T = 64;
    constexpr int KCH = H / 8;          // f16x8 chunks per A row
    constexpr int NFRAG = H / 64;       // 16-col fragments per wave
    constexpr int KSTEPS = H / 32;
    constexpr int SPITCH = 68;          // col-major S pitch (f16 elems)
    constexpr int LDSN = (H * SPITCH > T * H) ? H * SPITCH : T * H;
    static_assert(H % 64 == 0, "H multiple of 64");

    __shared__ _Float16 LDSBUF[LDSN];
    _Float16* A = LDSBUF;               // during MFMA phase
    _Float16* S = LDSBUF;               // after barrier: h2 dump (col-major)
    __shared__ int s_dst[T];
    __shared__ int s_src[T];

    const int tid = threadIdx.x;
    const int e0 = blockIdx.x * T;
    int nvalid = nE - e0; if (nvalid > T) nvalid = T;

    if (tid < T) { int e = e0 + tid; s_dst[tid] = (e < nE) ? sdst[e] : sdst[nE - 1]; }
    else if (tid < 2 * T) { int e = e0 + tid - T; s_src[tid - T] = (e < nE) ? ssrc[e] : 0; }
    __syncthreads();

    // gather + h1 = relu(P[dst] + Q[src]) -> swizzled LDS (f16)
    for (int q = tid; q < T * KCH; q += 256) {
        int row = q / KCH, kc = q % KCH;
        f16x8 pv = *(const f16x8*)&P[(size_t)s_dst[row] * H + kc * 8];
        f16x8 qv = *(const f16x8*)&Q[(size_t)s_src[row] * H + kc * 8];
        f16x8 h;
#pragma unroll
        for (int j = 0; j < 8; ++j) {
            _Float16 v = (_Float16)(pv[j] + qv[j]);
            h[j] = v > (_Float16)0.f ? v : (_Float16)0.f;
        }
        int byte = row * (2 * H) + kc * 16;
        byte ^= ((row & 7) << 4);
        *(f16x8*)((char*)A + byte) = h;
    }
    __syncthreads();

    // MFMA: h2_pre = h1 @ W2 + b2
    const int wave = tid >> 6, lane = tid & 63;
    const int c0 = wave * (H / 4);
    const int lr = lane & 15;
    const int kg = lane >> 4;

    f32x4 acc[4][NFRAG];
#pragma unroll
    for (int n = 0; n < NFRAG; ++n) {
        float bv = b2[c0 + n * 16 + lr];
#pragma unroll
        for (int m = 0; m < 4; ++m) acc[m][n] = (f32x4){bv, bv, bv, bv};
    }

    for (int ks = 0; ks < KSTEPS; ++ks) {
        const int k0 = ks * 32 + kg * 8;
        f16x8 af[4];
#pragma unroll
        for (int m = 0; m < 4; ++m) {
            int row = m * 16 + lr;
            int byte = row * (2 * H) + k0 * 2;
            byte ^= ((row & 7) << 4);
            af[m] = *(const f16x8*)((char*)A + byte);
        }
        f16x8 bf[NFRAG];
#pragma unroll
        for (int n = 0; n < NFRAG; ++n)
            bf[n] = *(const f16x8*)&W2T[(size_t)(c0 + n * 16 + lr) * H + k0];
#pragma unroll
        for (int m = 0; m < 4; ++m)
#pragma unroll
            for (int n = 0; n < NFRAG; ++n)
                acc[m][n] = __builtin_amdgcn_mfma_f32_16x16x32_f16(af[m], bf[n], acc[m][n], 0, 0, 0);
    }
    __syncthreads();   // everyone done reading A

    // dump h2 = relu(acc) -> S col-major f16; pack the 4 j-rows per b64 write
#pragma unroll
    for (int m = 0; m < 4; ++m)
#pragma unroll
        for (int n = 0; n < NFRAG; ++n) {
            int col = c0 + n * 16 + lr;
            int row0 = m * 16 + kg * 4;
            f16x4 v;
#pragma unroll
            for (int j = 0; j < 4; ++j) v[j] = (_Float16)fmaxf(acc[m][n][j], 0.f);
            *(f16x4*)&S[col * SPITCH + row0] = v;
        }
    __syncthreads();

    // segmented (sorted-dst) column reduction; wave-uniform branches
    {
        constexpr int CH = 256 / H;     // row chunks (1,2,4)
        constexpr int RPC = T / CH;     // rows per chunk (64,32,16)
        int c = tid % H;
        int ch = tid / H;
        int r0 = ch * RPC;
        int rend = r0 + RPC; if (rend > nvalid) rend = nvalid;
        if (r0 < nvalid) {
            int cur = s_dst[r0];
            float a = 0.f;
            for (int rb = r0; rb < rend; rb += 8) {
                f16x8 v = *(const f16x8*)&S[c * SPITCH + rb];
#pragma unroll
                for (int j = 0; j < 8; ++j) {
                    int r = rb + j;
                    if (r >= rend) break;
                    int d = s_dst[r];
                    if (d != cur) {
                        atomicAdd(&h2sum[(size_t)cur * H + c], a);
                        a = 0.f; cur = d;
                    }
                    a += (float)v[j];
                }
            }
            atomicAdd(&h2sum[(size_t)cur * H + c], a);
        }
    }
}

// ---------------------------------------------------------------------------
// x_out = h2sum @ W3 + deg * b3   (fp32)
// ---------------------------------------------------------------------------
template<int H>
__global__ __launch_bounds__(256) void w3_apply4(
    const float* __restrict__ h2sum, const float* __restrict__ w3,
    const float* __restrict__ b3, const int* __restrict__ deg,
    float* __restrict__ xout, int nNodes)
{
    int idx = blockIdx.x * 256 + threadIdx.x;
    int total = nNodes * (H / 4);
    if (idx >= total) return;
    int n = idx / (H / 4), j4 = (idx % (H / 4)) * 4;
    float dg = (float)deg[n];
    float4 b = *(const float4*)&b3[j4];
    float4 a = make_float4(b.x * dg, b.y * dg, b.z * dg, b.w * dg);
    const float* hr = h2sum + (size_t)n * H;
    for (int k = 0; k < H; ++k) {
        float s = hr[k];
        float4 w = *(const float4*)&w3[(size_t)k * H + j4];
        a.x += s * w.x; a.y += s * w.y; a.z += s * w.z; a.w += s * w.w;
    }
    *(float4*)&xout[(size_t)n * H + j4] = a;
}

// ---------------------------------------------------------------------------
// Pool: batch is sorted -> one block per graph, binary-search node range.
// ---------------------------------------------------------------------------
__global__ __launch_bounds__(256) void pool_graph(
    const float* __restrict__ x3, const int* __restrict__ batch,
    float* __restrict__ gsum, float* __restrict__ gcnt, int nNodes)
{
    int g = blockIdx.x;
    // lower_bound(batch, g) and lower_bound(batch, g+1)
    int lo = 0, hi = nNodes;
    while (lo < hi) { int mid = (lo + hi) >> 1; if (batch[mid] < g) lo = mid + 1; else hi = mid; }
    int lo2 = lo, hi2 = nNodes;
    while (lo2 < hi2) { int mid = (lo2 + hi2) >> 1; if (batch[mid] < g + 1) lo2 = mid + 1; else hi2 = mid; }
    int c = threadIdx.x;
    float s = 0.f;
    for (int n = lo; n < lo2; ++n) s += x3[(size_t)n * 256 + c];
    gsum[(size_t)g * 256 + c] = s;
    if (c == 0) gcnt[g] = (float)(lo2 - lo);
}

// ---------------------------------------------------------------------------
// Head
// ---------------------------------------------------------------------------
__global__ __launch_bounds__(256) void head(
    const float* __restrict__ gsum, const float* __restrict__ gcnt,
    const float* __restrict__ l2w, const float* __restrict__ l2b,
    const float* __restrict__ l3w, const float* __restrict__ l3b,
    float* __restrict__ out)
{
    __shared__ float g[N_GRAPHS * 256];
    __shared__ float h[N_GRAPHS * 64];
    int tid = threadIdx.x;
    for (int i = tid; i < N_GRAPHS * 256; i += 256) {
        int gi = i / 256;
        float c = gcnt[gi];
        g[i] = gsum[i] / fmaxf(c, 1.f);
    }
    __syncthreads();
    for (int i = tid; i < N_GRAPHS * 64; i += 256) {
        int r = i / 64, c = i - r * 64;
        float acc = l2b[c];
#pragma unroll 4
        for (int k = 0; k < 256; ++k) acc += g[r * 256 + k] * l2w[k * 64 + c];
        h[i] = acc;
    }
    __syncthreads();
    for (int i = tid; i < N_GRAPHS * 2; i += 256) {
        int r = i / 2, c = i - r * 2;
        float acc = l3b[c];
#pragma unroll 4
        for (int k = 0; k < 64; ++k) acc += h[r * 64 + k] * l3w[k * 2 + c];
        out[i] = 1.f / (1.f + expf(-acc));
    }
}

// ---------------------------------------------------------------------------
extern "C" void kernel_launch(void* const* d_in, const int* in_sizes, int n_in,
                              void* d_out, int out_size, void* d_ws, size_t ws_size,
                              hipStream_t stream)
{
    const float* x     = (const float*)d_in[0];
    const int*   ei    = (const int*)d_in[1];
    const int*   batch = (const int*)d_in[2];
    const float* c1_w1 = (const float*)d_in[3];
    const float* c1_b1 = (const float*)d_in[4];
    const float* c1_w2 = (const float*)d_in[5];
    const float* c1_b2 = (const float*)d_in[6];
    const float* c1_w3 = (const float*)d_in[7];
    const float* c1_b3 = (const float*)d_in[8];
    const float* c2_w1 = (const float*)d_in[9];
    const float* c2_b1 = (const float*)d_in[10];
    const float* c2_w2 = (const float*)d_in[11];
    const float* c2_b2 = (const float*)d_in[12];
    const float* c2_w3 = (const float*)d_in[13];
    const float* c2_b3 = (const float*)d_in[14];
    const float* c3_w1 = (const float*)d_in[15];
    const float* c3_b1 = (const float*)d_in[16];
    const float* c3_w2 = (const float*)d_in[17];
    const float* c3_b2 = (const float*)d_in[18];
    const float* c3_w3 = (const float*)d_in[19];
    const float* c3_b3 = (const float*)d_in[20];
    const float* l2w   = (const float*)d_in[21];
    const float* l2b   = (const float*)d_in[22];
    const float* l3w   = (const float*)d_in[23];
    const float* l3b   = (const float*)d_in[24];
    float* out = (float*)d_out;

    const int N = in_sizes[0] / 3;
    const int E = in_sizes[1] / 2;
    const int* src = ei;        // edge_index[0] = source j
    const int* dst = ei + E;    // edge_index[1] = target i

    // workspace layout
    float* ws   = (float*)d_ws;
    float* x1   = ws;                                   // N*64 f32
    float* x2   = x1 + (size_t)N * 64;                  // N*128 f32
    float* x3   = x2 + (size_t)N * 128;                 // N*256 f32
    _Float16* Ph = (_Float16*)(x3 + (size_t)N * 256);   // N*256 f16
    _Float16* Qh = Ph + (size_t)N * 256;                // N*256 f16
    float* h2s1 = (float*)(Qh + (size_t)N * 256);       // N*64  -- zero from here
    float* h2s2 = h2s1 + (size_t)N * 64;                // N*128
    float* h2s3 = h2s2 + (size_t)N * 128;               // N*256
    int*   hist   = (int*)(h2s3 + (size_t)N * 256);     // N  (deg) -- zero through here
    int*   cursor = hist + N;                           // N
    int*   ssrcb  = cursor + N;                         // E
    int*   sdstb  = ssrcb + E;                          // E
    float* gsum   = (float*)(sdstb + E);                // 64*256
    float* gcnt   = gsum + (size_t)N_GRAPHS * 256;      // 64
    _Float16* wt  = (_Float16*)(gcnt + N_GRAPHS);       // 256*256 f16

    size_t zero_bytes = (size_t)N * (64 + 128 + 256) * sizeof(float) + (size_t)N * sizeof(int);
    hipMemsetAsync(h2s1, 0, zero_bytes, stream);

    // sort edges by dst
    build_hist<<<(E + 255) / 256, 256, 0, stream>>>(dst, hist, E);
    scan_deg<<<1, 1024, 0, stream>>>(hist, cursor, N);
    scatter_edges<<<(E + 255) / 256, 256, 0, stream>>>(src, dst, cursor, ssrcb, sdstb, E);

    const int EB = (E + 63) / 64;

    // conv1: 3 -> 64
    node_pqh<3, 64><<<(N * 8 + 255) / 256, 256, 0, stream>>>(x, c1_w1, c1_b1, Ph, Qh, N);
    w2_to_t<64><<<(64 * 64 + 255) / 256, 256, 0, stream>>>(c1_w2, wt);
    edge_mfma<64><<<EB, 256, 0, stream>>>(Ph, Qh, ssrcb, sdstb, wt, c1_b2, h2s1, E);
    w3_apply4<64><<<(N * 16 + 255) / 256, 256, 0, stream>>>(h2s1, c1_w3, c1_b3, hist, x1, N);

    // conv2: 64 -> 128
    node_pqh<64, 128><<<(N * 16 + 255) / 256, 256, 0, stream>>>(x1, c2_w1, c2_b1, Ph, Qh, N);
    w2_to_t<128><<<(128 * 128 + 255) / 256, 256, 0, stream>>>(c2_w2, wt);
    edge_mfma<128><<<EB, 256, 0, stream>>>(Ph, Qh, ssrcb, sdstb, wt, c2_b2, h2s2, E);
    w3_apply4<128><<<(N * 32 + 255) / 256, 256, 0, stream>>>(h2s2, c2_w3, c2_b3, hist, x2, N);

    // conv3: 128 -> 256
    node_pqh<128, 256><<<(N * 32 + 255) / 256, 256, 0, stream>>>(x2, c3_w1, c3_b1, Ph, Qh, N);
    w2_to_t<256><<<(256 * 256 + 255) / 256, 256, 0, stream>>>(c3_w2, wt);
    edge_mfma<256><<<EB, 256, 0, stream>>>(Ph, Qh, ssrcb, sdstb, wt, c3_b2, h2s3, E);
    w3_apply4<256><<<(N * 64 + 255) / 256, 256, 0, stream>>>(h2s3, c3_w3, c3_b3, hist, x3, N);

    // pool + head
    pool_graph<<<N_GRAPHS, 256, 0, stream>>>(x3, batch, gsum, gcnt, N);
    head<<<1, 256, 0, stream>>>(gsum, gcnt, l2w, l2b, l3w, l3b, out);
}

// Round 4
// 382.656 us; speedup vs baseline: 12.1096x; 1.7159x over previous
//
#include <hip/hip_runtime.h>
#include <cmath>

#define N_GRAPHS 64

typedef _Float16 f16x8 __attribute__((ext_vector_type(8)));
typedef _Float16 f16x4 __attribute__((ext_vector_type(4)));
typedef float f32x4 __attribute__((ext_vector_type(4)));

// ---------------------------------------------------------------------------
// Counting sort of edges by dst
// ---------------------------------------------------------------------------
__global__ __launch_bounds__(256) void build_hist(
    const int* __restrict__ dst, int* __restrict__ hist, int E)
{
    int i = blockIdx.x * 256 + threadIdx.x;
    if (i < E) atomicAdd(&hist[dst[i]], 1);
}

__global__ __launch_bounds__(1024) void scan_deg(
    const int* __restrict__ hist, int* __restrict__ cursor, int N)
{
    __shared__ int part[1024];
    int tid = threadIdx.x;
    int per = (N + 1023) / 1024;
    int base = tid * per;
    int s = 0;
    for (int i = 0; i < per; ++i) { int idx = base + i; if (idx < N) s += hist[idx]; }
    part[tid] = s;
    __syncthreads();
    for (int off = 1; off < 1024; off <<= 1) {
        int v = (tid >= off) ? part[tid - off] : 0;
        __syncthreads();
        part[tid] += v;
        __syncthreads();
    }
    int run = part[tid] - s;
    for (int i = 0; i < per; ++i) {
        int idx = base + i;
        if (idx < N) { cursor[idx] = run; run += hist[idx]; }
    }
}

__global__ __launch_bounds__(256) void scatter_edges(
    const int* __restrict__ src, const int* __restrict__ dst,
    int* __restrict__ cursor, int* __restrict__ ssrc, int* __restrict__ sdst, int E)
{
    int i = blockIdx.x * 256 + threadIdx.x;
    if (i >= E) return;
    int d = dst[i];
    int pos = atomicAdd(&cursor[d], 1);
    ssrc[pos] = src[i];
    sdst[pos] = d;
}

// ---------------------------------------------------------------------------
// W2 [K][N] fp32 -> W2T [N][K] f16
// ---------------------------------------------------------------------------
template<int H>
__global__ __launch_bounds__(256) void w2_to_t(
    const float* __restrict__ w2, _Float16* __restrict__ wt)
{
    int idx = blockIdx.x * 256 + threadIdx.x;
    if (idx >= H * H) return;
    int n = idx / H, k = idx % H;
    wt[idx] = (_Float16)w2[k * H + n];
}

// ---------------------------------------------------------------------------
// Fused weights: PQWT[j][k] (f16, B^T) = (W3_prev @ W1part_cur)^T
//   j < HOUT: W1part = w1[m][j] - w1[K+m][j]   (P projection)
//   j >= HOUT: W1part = w1[K+m][j-HOUT]        (Q projection)
// ---------------------------------------------------------------------------
template<int K, int HOUT>
__global__ __launch_bounds__(256) void pqw_fuse(
    const float* __restrict__ w3, const float* __restrict__ w1,
    _Float16* __restrict__ pqwt)
{
    int idx = blockIdx.x * 256 + threadIdx.x;
    if (idx >= 2 * HOUT * K) return;
    int j = idx / K, k = idx % K;
    float acc = 0.f;
    if (j < HOUT) {
        for (int m = 0; m < K; ++m)
            acc += w3[k * K + m] * (w1[(size_t)m * HOUT + j] - w1[(size_t)(K + m) * HOUT + j]);
    } else {
        int jq = j - HOUT;
        for (int m = 0; m < K; ++m)
            acc += w3[k * K + m] * w1[(size_t)(K + m) * HOUT + jq];
    }
    pqwt[(size_t)j * K + k] = (_Float16)acc;
}

template<int K, int HOUT>
__global__ __launch_bounds__(256) void pqb_fuse(
    const float* __restrict__ w1, const float* __restrict__ b3,
    const float* __restrict__ b1, float* __restrict__ pb, float* __restrict__ bex)
{
    int j = blockIdx.x * 256 + threadIdx.x;
    if (j >= 2 * HOUT) return;
    float acc = 0.f;
    if (j < HOUT) {
        for (int m = 0; m < K; ++m)
            acc += b3[m] * (w1[(size_t)m * HOUT + j] - w1[(size_t)(K + m) * HOUT + j]);
        bex[j] = b1[j];
    } else {
        int jq = j - HOUT;
        for (int m = 0; m < K; ++m)
            acc += b3[m] * w1[(size_t)(K + m) * HOUT + jq];
        bex[j] = 0.f;
    }
    pb[j] = acc;
}

// ---------------------------------------------------------------------------
// conv1 P/Q from raw x (F=3)
// ---------------------------------------------------------------------------
template<int F, int H>
__global__ __launch_bounds__(256) void node_pqh(
    const float* __restrict__ x, const float* __restrict__ w1,
    const float* __restrict__ b1, _Float16* __restrict__ P,
    _Float16* __restrict__ Q, int nNodes)
{
    int idx = blockIdx.x * 256 + threadIdx.x;
    int total = nNodes * (H / 8);
    if (idx >= total) return;
    int n = idx / (H / 8), j8 = (idx % (H / 8)) * 8;
    float p[8], q[8];
#pragma unroll
    for (int j = 0; j < 8; ++j) { p[j] = b1[j8 + j]; q[j] = 0.f; }
    for (int k = 0; k < F; ++k) {
        float xv = x[(size_t)n * F + k];
        const float* wt = &w1[(size_t)k * H + j8];
        const float* wb = &w1[(size_t)(F + k) * H + j8];
        float4 t0 = *(const float4*)wt, t1 = *(const float4*)(wt + 4);
        float4 b0 = *(const float4*)wb, b1v = *(const float4*)(wb + 4);
        p[0] += xv * (t0.x - b0.x);  q[0] += xv * b0.x;
        p[1] += xv * (t0.y - b0.y);  q[1] += xv * b0.y;
        p[2] += xv * (t0.z - b0.z);  q[2] += xv * b0.z;
        p[3] += xv * (t0.w - b0.w);  q[3] += xv * b0.w;
        p[4] += xv * (t1.x - b1v.x); q[4] += xv * b1v.x;
        p[5] += xv * (t1.y - b1v.y); q[5] += xv * b1v.y;
        p[6] += xv * (t1.z - b1v.z); q[6] += xv * b1v.z;
        p[7] += xv * (t1.w - b1v.w); q[7] += xv * b1v.w;
    }
    f16x8 ph, qh;
#pragma unroll
    for (int j = 0; j < 8; ++j) { ph[j] = (_Float16)p[j]; qh[j] = (_Float16)q[j]; }
    *(f16x8*)&P[(size_t)n * H + j8] = ph;
    *(f16x8*)&Q[(size_t)n * H + j8] = qh;
}

// ---------------------------------------------------------------------------
// pq_gemm: [P|Q](f16) = f16GEMM(h2sum_prev, PQWT) + deg*pb + bex
//   M-tile 64 nodes/block, 4 waves split 2*HOUT cols.
// ---------------------------------------------------------------------------
template<int K, int HOUT>
__global__ __launch_bounds__(256) void pq_gemm(
    const float* __restrict__ h2sum, const _Float16* __restrict__ PQWT,
    const float* __restrict__ pb, const float* __restrict__ bex,
    const int* __restrict__ deg, _Float16* __restrict__ Ph,
    _Float16* __restrict__ Qh, int nNodes)
{
    constexpr int T = 64;
    constexpr int KCH = K / 8;
    constexpr int CPW = (2 * HOUT) / 4;   // cols per wave
    constexpr int NFRAG = CPW / 16;
    constexpr int KSTEPS = K / 32;

    __shared__ _Float16 A[T * K];
    __shared__ int sdeg[T];

    const int tid = threadIdx.x;
    const int n0 = blockIdx.x * T;

    if (tid < T) { int n = n0 + tid; sdeg[tid] = (n < nNodes) ? deg[n] : 0; }

    for (int q = tid; q < T * KCH; q += 256) {
        int row = q / KCH, kc = q % KCH;
        int n = n0 + row; if (n >= nNodes) n = nNodes - 1;
        const float* hr = h2sum + (size_t)n * K + kc * 8;
        float4 a0 = *(const float4*)hr, a1 = *(const float4*)(hr + 4);
        f16x8 h;
        h[0] = (_Float16)a0.x; h[1] = (_Float16)a0.y;
        h[2] = (_Float16)a0.z; h[3] = (_Float16)a0.w;
        h[4] = (_Float16)a1.x; h[5] = (_Float16)a1.y;
        h[6] = (_Float16)a1.z; h[7] = (_Float16)a1.w;
        int byte = row * (2 * K) + kc * 16;
        byte ^= ((row & 7) << 4);
        *(f16x8*)((char*)A + byte) = h;
    }
    __syncthreads();

    const int wave = tid >> 6, lane = tid & 63;
    const int c0 = wave * CPW;
    const int lr = lane & 15;
    const int kg = lane >> 4;

    f32x4 acc[4][NFRAG];
#pragma unroll
    for (int m = 0; m < 4; ++m)
#pragma unroll
        for (int n = 0; n < NFRAG; ++n) acc[m][n] = (f32x4){0.f, 0.f, 0.f, 0.f};

    for (int ks = 0; ks < KSTEPS; ++ks) {
        const int k0 = ks * 32 + kg * 8;
        f16x8 af[4];
#pragma unroll
        for (int m = 0; m < 4; ++m) {
            int row = m * 16 + lr;
            int byte = row * (2 * K) + k0 * 2;
            byte ^= ((row & 7) << 4);
            af[m] = *(const f16x8*)((char*)A + byte);
        }
        f16x8 bf[NFRAG];
#pragma unroll
        for (int n = 0; n < NFRAG; ++n)
            bf[n] = *(const f16x8*)&PQWT[(size_t)(c0 + n * 16 + lr) * K + k0];
#pragma unroll
        for (int m = 0; m < 4; ++m)
#pragma unroll
            for (int n = 0; n < NFRAG; ++n)
                acc[m][n] = __builtin_amdgcn_mfma_f32_16x16x32_f16(af[m], bf[n], acc[m][n], 0, 0, 0);
    }

    // epilogue: + deg*pb + bex, store f16 to Ph / Qh
#pragma unroll
    for (int m = 0; m < 4; ++m)
#pragma unroll
        for (int n = 0; n < NFRAG; ++n) {
            int col = c0 + n * 16 + lr;
            float pbv = pb[col], bexv = bex[col];
            int row0 = m * 16 + kg * 4;
#pragma unroll
            for (int j = 0; j < 4; ++j) {
                int row = row0 + j;
                int node = n0 + row;
                if (node < nNodes) {
                    float v = acc[m][n][j] + (float)sdeg[row] * pbv + bexv;
                    if (col < HOUT) Ph[(size_t)node * HOUT + col] = (_Float16)v;
                    else            Qh[(size_t)node * HOUT + col - HOUT] = (_Float16)v;
                }
            }
        }
}

// ---------------------------------------------------------------------------
// Per-edge layer-2 MFMA + in-tile segmented reduction (XCD-chunked swizzle).
// ---------------------------------------------------------------------------
template<int H>
__global__ __launch_bounds__(256, 4) void edge_mfma(
    const _Float16* __restrict__ P, const _Float16* __restrict__ Q,
    const int* __restrict__ ssrc, const int* __restrict__ sdst,
    const _Float16* __restrict__ W2T, const float* __restrict__ b2,
    float* __restrict__ h2sum, int nE)
{
    constexpr int T = 64;
    constexpr int KCH = H / 8;
    constexpr int NFRAG = H / 64;
    constexpr int KSTEPS = H / 32;
    constexpr int SPITCH = 68;
    constexpr int LDSN = (H * SPITCH > T * H) ? H * SPITCH : T * H;
    static_assert(H % 64 == 0, "H multiple of 64");

    __shared__ _Float16 LDSBUF[LDSN];
    _Float16* A = LDSBUF;
    _Float16* S = LDSBUF;
    __shared__ int s_dst[T];
    __shared__ int s_src[T];

    // XCD-chunked bijective swizzle: consecutive dst-ranges per XCD
    int bid = blockIdx.x;
    {
        int nwg = gridDim.x;
        if ((nwg & 7) == 0) {
            int per = nwg >> 3;
            bid = (bid & 7) * per + (bid >> 3);
        }
    }

    const int tid = threadIdx.x;
    const int e0 = bid * T;
    int nvalid = nE - e0; if (nvalid > T) nvalid = T;

    if (tid < T) { int e = e0 + tid; s_dst[tid] = (e < nE) ? sdst[e] : sdst[nE - 1]; }
    else if (tid < 2 * T) { int e = e0 + tid - T; s_src[tid - T] = (e < nE) ? ssrc[e] : 0; }
    __syncthreads();

    for (int q = tid; q < T * KCH; q += 256) {
        int row = q / KCH, kc = q % KCH;
        f16x8 pv = *(const f16x8*)&P[(size_t)s_dst[row] * H + kc * 8];
        f16x8 qv = *(const f16x8*)&Q[(size_t)s_src[row] * H + kc * 8];
        f16x8 h;
#pragma unroll
        for (int j = 0; j < 8; ++j) {
            _Float16 v = (_Float16)(pv[j] + qv[j]);
            h[j] = v > (_Float16)0.f ? v : (_Float16)0.f;
        }
        int byte = row * (2 * H) + kc * 16;
        byte ^= ((row & 7) << 4);
        *(f16x8*)((char*)A + byte) = h;
    }
    __syncthreads();

    const int wave = tid >> 6, lane = tid & 63;
    const int c0 = wave * (H / 4);
    const int lr = lane & 15;
    const int kg = lane >> 4;

    f32x4 acc[4][NFRAG];
#pragma unroll
    for (int n = 0; n < NFRAG; ++n) {
        float bv = b2[c0 + n * 16 + lr];
#pragma unroll
        for (int m = 0; m < 4; ++m) acc[m][n] = (f32x4){bv, bv, bv, bv};
    }

    for (int ks = 0; ks < KSTEPS; ++ks) {
        const int k0 = ks * 32 + kg * 8;
        f16x8 af[4];
#pragma unroll
        for (int m = 0; m < 4; ++m) {
            int row = m * 16 + lr;
            int byte = row * (2 * H) + k0 * 2;
            byte ^= ((row & 7) << 4);
            af[m] = *(const f16x8*)((char*)A + byte);
        }
        f16x8 bf[NFRAG];
#pragma unroll
        for (int n = 0; n < NFRAG; ++n)
            bf[n] = *(const f16x8*)&W2T[(size_t)(c0 + n * 16 + lr) * H + k0];
#pragma unroll
        for (int m = 0; m < 4; ++m)
#pragma unroll
            for (int n = 0; n < NFRAG; ++n)
                acc[m][n] = __builtin_amdgcn_mfma_f32_16x16x32_f16(af[m], bf[n], acc[m][n], 0, 0, 0);
    }
    __syncthreads();

    // dump h2 = relu(acc) -> S col-major f16 (pitch 68)
#pragma unroll
    for (int m = 0; m < 4; ++m)
#pragma unroll
        for (int n = 0; n < NFRAG; ++n) {
            int col = c0 + n * 16 + lr;
            int row0 = m * 16 + kg * 4;
            f16x4 v;
#pragma unroll
            for (int j = 0; j < 4; ++j) v[j] = (_Float16)fmaxf(acc[m][n][j], 0.f);
            *(f16x4*)&S[col * SPITCH + row0] = v;
        }
    __syncthreads();

    // segmented (sorted-dst) column reduction
    {
        constexpr int CH = 256 / H;
        constexpr int RPC = T / CH;
        int c = tid % H;
        int ch = tid / H;
        int r0 = ch * RPC;
        int rend = r0 + RPC; if (rend > nvalid) rend = nvalid;
        if (r0 < nvalid) {
            int cur = s_dst[r0];
            float a = 0.f;
            for (int rb = r0; rb < rend; rb += 8) {
                f16x8 v = *(const f16x8*)&S[c * SPITCH + rb];
#pragma unroll
                for (int j = 0; j < 8; ++j) {
                    int r = rb + j;
                    if (r >= rend) break;
                    int d = s_dst[r];
                    if (d != cur) {
                        atomicAdd(&h2sum[(size_t)cur * H + c], a);
                        a = 0.f; cur = d;
                    }
                    a += (float)v[j];
                }
            }
            atomicAdd(&h2sum[(size_t)cur * H + c], a);
        }
    }
}

// ---------------------------------------------------------------------------
// Pool h2s3 per graph (sum over nodes) + count + edge-degree sum.
// ---------------------------------------------------------------------------
__global__ __launch_bounds__(256) void pool_h(
    const float* __restrict__ h2s3, const int* __restrict__ batch,
    const int* __restrict__ cursor, float* __restrict__ gsumh,
    float* __restrict__ gcnt, float* __restrict__ gdeg, int nNodes)
{
    int g = blockIdx.x;
    int lo = 0, hi = nNodes;
    while (lo < hi) { int mid = (lo + hi) >> 1; if (batch[mid] < g) lo = mid + 1; else hi = mid; }
    int lo2 = lo, hi2 = nNodes;
    while (lo2 < hi2) { int mid = (lo2 + hi2) >> 1; if (batch[mid] < g + 1) lo2 = mid + 1; else hi2 = mid; }
    int c = threadIdx.x;
    float s = 0.f;
    for (int n = lo; n < lo2; ++n) s += h2s3[(size_t)n * 256 + c];
    gsumh[(size_t)g * 256 + c] = s;
    if (c == 0) {
        gcnt[g] = (float)(lo2 - lo);
        int e1 = (lo2 > 0) ? cursor[lo2 - 1] : 0;   // cursor[n] = end offset of node n
        int e0 = (lo > 0) ? cursor[lo - 1] : 0;
        gdeg[g] = (float)(e1 - e0);
    }
}

// ---------------------------------------------------------------------------
// Head: one block per graph.  x3_mean = (gsumh@W3 + gdeg*b3)/cnt ; l2 ; l3 ; sigmoid
// ---------------------------------------------------------------------------
__global__ __launch_bounds__(256) void head64(
    const float* __restrict__ gsumh, const float* __restrict__ gcnt,
    const float* __restrict__ gdeg, const float* __restrict__ w3,
    const float* __restrict__ b3, const float* __restrict__ l2w,
    const float* __restrict__ l2b, const float* __restrict__ l3w,
    const float* __restrict__ l3b, float* __restrict__ out)
{
    __shared__ float gh[256];
    __shared__ float gm[256];
    __shared__ float hp[4][64];
    __shared__ float hv[64];
    int g = blockIdx.x, tid = threadIdx.x;
    gh[tid] = gsumh[(size_t)g * 256 + tid];
    __syncthreads();
    float dg = gdeg[g], cnt = fmaxf(gcnt[g], 1.f);
    float acc = dg * b3[tid];
#pragma unroll 4
    for (int k = 0; k < 256; ++k) acc += gh[k] * w3[(size_t)k * 256 + tid];
    gm[tid] = acc / cnt;
    __syncthreads();
    int c = tid & 63, q = tid >> 6;
    float a2 = 0.f;
#pragma unroll 4
    for (int kk = 0; kk < 64; ++kk) {
        int k = q * 64 + kk;
        a2 += gm[k] * l2w[(size_t)k * 64 + c];
    }
    hp[q][c] = a2;
    __syncthreads();
    if (tid < 64) hv[tid] = hp[0][tid] + hp[1][tid] + hp[2][tid] + hp[3][tid] + l2b[tid];
    __syncthreads();
    if (tid < 2) {
        float a3 = l3b[tid];
#pragma unroll 4
        for (int k = 0; k < 64; ++k) a3 += hv[k] * l3w[k * 2 + tid];
        out[g * 2 + tid] = 1.f / (1.f + expf(-a3));
    }
}

// ---------------------------------------------------------------------------
extern "C" void kernel_launch(void* const* d_in, const int* in_sizes, int n_in,
                              void* d_out, int out_size, void* d_ws, size_t ws_size,
                              hipStream_t stream)
{
    const float* x     = (const float*)d_in[0];
    const int*   ei    = (const int*)d_in[1];
    const int*   batch = (const int*)d_in[2];
    const float* c1_w1 = (const float*)d_in[3];
    const float* c1_b1 = (const float*)d_in[4];
    const float* c1_w2 = (const float*)d_in[5];
    const float* c1_b2 = (const float*)d_in[6];
    const float* c1_w3 = (const float*)d_in[7];
    const float* c1_b3 = (const float*)d_in[8];
    const float* c2_w1 = (const float*)d_in[9];
    const float* c2_b1 = (const float*)d_in[10];
    const float* c2_w2 = (const float*)d_in[11];
    const float* c2_b2 = (const float*)d_in[12];
    const float* c2_w3 = (const float*)d_in[13];
    const float* c2_b3 = (const float*)d_in[14];
    const float* c3_w1 = (const float*)d_in[15];
    const float* c3_b1 = (const float*)d_in[16];
    const float* c3_w2 = (const float*)d_in[17];
    const float* c3_b2 = (const float*)d_in[18];
    const float* c3_w3 = (const float*)d_in[19];
    const float* c3_b3 = (const float*)d_in[20];
    const float* l2w   = (const float*)d_in[21];
    const float* l2b   = (const float*)d_in[22];
    const float* l3w   = (const float*)d_in[23];
    const float* l3b   = (const float*)d_in[24];
    float* out = (float*)d_out;

    const int N = in_sizes[0] / 3;
    const int E = in_sizes[1] / 2;
    const int* src = ei;
    const int* dst = ei + E;

    // workspace layout
    float* h2s1 = (float*)d_ws;                          // N*64   -- zero from here
    float* h2s2 = h2s1 + (size_t)N * 64;                 // N*128
    float* h2s3 = h2s2 + (size_t)N * 128;                // N*256
    int*   hist   = (int*)(h2s3 + (size_t)N * 256);      // N (deg) -- zero through here
    int*   cursor = hist + N;                            // N
    int*   ssrcb  = cursor + N;                          // E
    int*   sdstb  = ssrcb + E;                           // E
    _Float16* Ph  = (_Float16*)(sdstb + E);              // N*256 f16 (max H)
    _Float16* Qh  = Ph + (size_t)N * 256;                // N*256 f16
    _Float16* wt  = Qh + (size_t)N * 256;                // 256*256 f16
    _Float16* pqwt2 = wt + 256 * 256;                    // 256*64 f16
    _Float16* pqwt3 = pqwt2 + 256 * 64;                  // 512*128 f16
    float* pb2   = (float*)(pqwt3 + 512 * 128);          // 256
    float* bex2  = pb2 + 256;                            // 256
    float* pb3   = bex2 + 256;                           // 512
    float* bex3  = pb3 + 512;                            // 512
    float* gsumh = bex3 + 512;                           // 64*256
    float* gcnt  = gsumh + (size_t)N_GRAPHS * 256;       // 64
    float* gdeg  = gcnt + N_GRAPHS;                      // 64

    size_t zero_bytes = (size_t)N * (64 + 128 + 256) * sizeof(float) + (size_t)N * sizeof(int);
    hipMemsetAsync(h2s1, 0, zero_bytes, stream);

    // sort edges by dst
    build_hist<<<(E + 255) / 256, 256, 0, stream>>>(dst, hist, E);
    scan_deg<<<1, 1024, 0, stream>>>(hist, cursor, N);
    scatter_edges<<<(E + 255) / 256, 256, 0, stream>>>(src, dst, cursor, ssrcb, sdstb, E);

    // fused P/Q weights for conv2 and conv3 (independent of node data)
    pqw_fuse<64, 128><<<(2 * 128 * 64 + 255) / 256, 256, 0, stream>>>(c1_w3, c2_w1, pqwt2);
    pqb_fuse<64, 128><<<(2 * 128 + 255) / 256, 256, 0, stream>>>(c2_w1, c1_b3, c2_b1, pb2, bex2);
    pqw_fuse<128, 256><<<(2 * 256 * 128 + 255) / 256, 256, 0, stream>>>(c2_w3, c3_w1, pqwt3);
    pqb_fuse<128, 256><<<(2 * 256 + 255) / 256, 256, 0, stream>>>(c3_w1, c2_b3, c3_b1, pb3, bex3);

    const int EB = (E + 63) / 64;
    const int NB = (N + 63) / 64;

    // conv1: 3 -> 64
    node_pqh<3, 64><<<(N * 8 + 255) / 256, 256, 0, stream>>>(x, c1_w1, c1_b1, Ph, Qh, N);
    w2_to_t<64><<<(64 * 64 + 255) / 256, 256, 0, stream>>>(c1_w2, wt);
    edge_mfma<64><<<EB, 256, 0, stream>>>(Ph, Qh, ssrcb, sdstb, wt, c1_b2, h2s1, E);

    // conv2: P/Q = fused(h2s1) ; edges
    pq_gemm<64, 128><<<NB, 256, 0, stream>>>(h2s1, pqwt2, pb2, bex2, hist, Ph, Qh, N);
    w2_to_t<128><<<(128 * 128 + 255) / 256, 256, 0, stream>>>(c2_w2, wt);
    edge_mfma<128><<<EB, 256, 0, stream>>>(Ph, Qh, ssrcb, sdstb, wt, c2_b2, h2s2, E);

    // conv3
    pq_gemm<128, 256><<<NB, 256, 0, stream>>>(h2s2, pqwt3, pb3, bex3, hist, Ph, Qh, N);
    w2_to_t<256><<<(256 * 256 + 255) / 256, 256, 0, stream>>>(c3_w2, wt);
    edge_mfma<256><<<EB, 256, 0, stream>>>(Ph, Qh, ssrcb, sdstb, wt, c3_b2, h2s3, E);

    // pool (linear: W3 applied to pooled sums in head) + head
    pool_h<<<N_GRAPHS, 256, 0, stream>>>(h2s3, batch, cursor, gsumh, gcnt, gdeg, N);
    head64<<<N_GRAPHS, 256, 0, stream>>>(gsumh, gcnt, gdeg, c3_w3, c3_b3, l2w, l2b, l3w, l3b, out);
}